// Round 1
// baseline (2879.035 us; speedup 1.0000x reference)
//
#include <hip/hip_runtime.h>

// GCN: 2x GCNConv(128->128) + linear head (128->64), N=50000, E=800000.
// All f32 (reference dtype). Layout of work:
//   dinv  : [N]  deg^{-1/2} (computed from dst + self loops)
//   bufA  : [N,128] GEMM outputs (h = x@W)
//   bufB  : [N,128] aggregation buffer (init with self-loop term, then
//                   atomicAdd over edges)

constexpr int DIM = 128;

// ---------------------------------------------------------------- degree ----
__global__ __launch_bounds__(256) void k_deg_init(float* deg, int n) {
    int i = blockIdx.x * 256 + threadIdx.x;
    if (i < n) deg[i] = 1.0f;   // self loop
}

__global__ __launch_bounds__(256) void k_deg_count(const int* __restrict__ dst,
                                                   float* deg, int e) {
    int i = blockIdx.x * 256 + threadIdx.x;
    if (i < e) atomicAdd(&deg[dst[i]], 1.0f);
}

__global__ __launch_bounds__(256) void k_rsqrt(float* deg, int n) {
    int i = blockIdx.x * 256 + threadIdx.x;
    if (i < n) deg[i] = rsqrtf(deg[i]);
}

// ------------------------------------------------- self-loop init of agg ----
// agg[i,:] = h[i,:] * dinv[i]^2   (self-loop norm), float4 per thread
__global__ __launch_bounds__(256) void k_selfloop(const float* __restrict__ h,
                                                  const float* __restrict__ dinv,
                                                  float* __restrict__ agg, int n) {
    int i = blockIdx.x * 256 + threadIdx.x;       // float4 index
    int total = n * (DIM / 4);
    if (i < total) {
        int row = i / (DIM / 4);
        float d = dinv[row];
        float s = d * d;
        float4 v = ((const float4*)h)[i];
        v.x *= s; v.y *= s; v.z *= s; v.w *= s;
        ((float4*)agg)[i] = v;
    }
}

// ------------------------------------------------------- edge scatter-add ----
// 32 threads per edge, each handles 4 contiguous floats (float4 gather,
// 4x atomicAdd scatter).
__global__ __launch_bounds__(256) void k_edge_agg(const int* __restrict__ src,
                                                  const int* __restrict__ dst,
                                                  const float* __restrict__ dinv,
                                                  const float* __restrict__ h,
                                                  float* __restrict__ agg, int e) {
    long long t = (long long)blockIdx.x * 256 + threadIdx.x;
    int edge = (int)(t >> 5);
    int lane = (int)(t & 31);
    if (edge < e) {
        int s = src[edge];
        int d = dst[edge];
        float w = dinv[s] * dinv[d];
        const float* hp = h + (size_t)s * DIM + lane * 4;
        float4 v = *(const float4*)hp;
        float* out = agg + (size_t)d * DIM + lane * 4;
        atomicAdd(out + 0, v.x * w);
        atomicAdd(out + 1, v.y * w);
        atomicAdd(out + 2, v.z * w);
        atomicAdd(out + 3, v.w * w);
    }
}

// ----------------------------------------------------------------- GEMM -----
// C[n,NCOL] = epilogue_in(A[n,128]) @ B[128,NCOL] (+ bias_out)
// epilogue_in: optional +bias_in then optional relu (applied when staging A).
// B fully staged in LDS (natural [k][c] layout -> conflict-free b64 reads),
// A tile (32 rows) staged in LDS, register tile 2 cols x RPT rows per thread.
template <int NCOL>
__global__ __launch_bounds__(256) void gemm_kernel(
    const float* __restrict__ A, const float* __restrict__ B,
    float* __restrict__ C,
    const float* __restrict__ bias_in, const float* __restrict__ bias_out,
    int relu_in, int n) {
    constexpr int K = DIM;
    constexpr int ROWS = 32;
    constexpr int CH = NCOL / 2;   // col-pair groups per row-group (64 or 32)
    constexpr int G = 256 / CH;    // row groups (4 or 8)
    constexpr int RPT = ROWS / G;  // rows per thread (8 or 4)

    __shared__ float Bs[K * NCOL];
    __shared__ float As[ROWS * K];

    int tid = threadIdx.x;
    int row0 = blockIdx.x * ROWS;

    // stage B (reused by every block; L2-resident)
    for (int i = tid * 4; i < K * NCOL; i += 1024)
        *(float4*)&Bs[i] = *(const float4*)&B[i];

    // stage A tile with optional input epilogue
    for (int i = tid * 4; i < ROWS * K; i += 1024) {
        int r = i >> 7;         // /128
        int k = i & (K - 1);
        int row = row0 + r;
        float4 v = make_float4(0.f, 0.f, 0.f, 0.f);
        if (row < n) {
            v = *(const float4*)&A[(size_t)row * K + k];
            if (bias_in) {
                v.x += bias_in[k + 0];
                v.y += bias_in[k + 1];
                v.z += bias_in[k + 2];
                v.w += bias_in[k + 3];
            }
            if (relu_in) {
                v.x = fmaxf(v.x, 0.f);
                v.y = fmaxf(v.y, 0.f);
                v.z = fmaxf(v.z, 0.f);
                v.w = fmaxf(v.w, 0.f);
            }
        }
        *(float4*)&As[i] = v;
    }
    __syncthreads();

    int c2 = (tid % CH) * 2;
    int rg = tid / CH;

    float acc[RPT][2];
#pragma unroll
    for (int r = 0; r < RPT; ++r) { acc[r][0] = 0.f; acc[r][1] = 0.f; }

    for (int k = 0; k < K; k += 4) {
        float2 b0 = *(const float2*)&Bs[(k + 0) * NCOL + c2];
        float2 b1 = *(const float2*)&Bs[(k + 1) * NCOL + c2];
        float2 b2 = *(const float2*)&Bs[(k + 2) * NCOL + c2];
        float2 b3 = *(const float2*)&Bs[(k + 3) * NCOL + c2];
#pragma unroll
        for (int r = 0; r < RPT; ++r) {
            float4 a4 = *(const float4*)&As[(rg * RPT + r) * K + k];
            acc[r][0] += a4.x * b0.x + a4.y * b1.x + a4.z * b2.x + a4.w * b3.x;
            acc[r][1] += a4.x * b0.y + a4.y * b1.y + a4.z * b2.y + a4.w * b3.y;
        }
    }

#pragma unroll
    for (int r = 0; r < RPT; ++r) {
        int row = row0 + rg * RPT + r;
        if (row < n) {
            float o0 = acc[r][0];
            float o1 = acc[r][1];
            if (bias_out) {
                o0 += bias_out[c2 + 0];
                o1 += bias_out[c2 + 1];
            }
            *(float2*)&C[(size_t)row * NCOL + c2] = make_float2(o0, o1);
        }
    }
}

// --------------------------------------------------------------- launch -----
extern "C" void kernel_launch(void* const* d_in, const int* in_sizes, int n_in,
                              void* d_out, int out_size, void* d_ws, size_t ws_size,
                              hipStream_t stream) {
    const float* x  = (const float*)d_in[0];
    const int*   ei = (const int*)d_in[1];
    const float* W1 = (const float*)d_in[2];
    const float* b1 = (const float*)d_in[3];
    const float* W2 = (const float*)d_in[4];
    const float* b2 = (const float*)d_in[5];
    const float* Wh = (const float*)d_in[6];
    const float* bh = (const float*)d_in[7];
    float* out = (float*)d_out;

    const int n = in_sizes[0] / DIM;       // 50000
    const int e = in_sizes[1] / 2;         // 800000
    const int* src = ei;
    const int* dst = ei + e;

    float* dinv = (float*)d_ws;
    size_t nAlign = ((size_t)n + 255) & ~(size_t)255;
    float* bufA = dinv + nAlign;                 // [n,128] gemm output
    float* bufB = bufA + (size_t)n * DIM;        // [n,128] aggregation

    int gbN   = (n + 255) / 256;
    int gbE   = (e + 255) / 256;
    int gbNC  = (n * (DIM / 4) + 255) / 256;
    int gbE32 = (int)(((long long)e * 32 + 255) / 256);
    int gbG   = (n + 31) / 32;

    // degrees -> dinv
    k_deg_init<<<gbN, 256, 0, stream>>>(dinv, n);
    k_deg_count<<<gbE, 256, 0, stream>>>(dst, dinv, e);
    k_rsqrt<<<gbN, 256, 0, stream>>>(dinv, n);

    // layer 1: bufA = x @ W1 ; bufB = selfloop + edge aggregation
    gemm_kernel<DIM><<<gbG, 256, 0, stream>>>(x, W1, bufA, nullptr, nullptr, 0, n);
    k_selfloop<<<gbNC, 256, 0, stream>>>(bufA, dinv, bufB, n);
    k_edge_agg<<<gbE32, 256, 0, stream>>>(src, dst, dinv, bufA, bufB, e);

    // layer 2: bufA = relu(bufB + b1) @ W2 ; bufB = selfloop + edge agg
    gemm_kernel<DIM><<<gbG, 256, 0, stream>>>(bufB, W2, bufA, b1, nullptr, 1, n);
    k_selfloop<<<gbNC, 256, 0, stream>>>(bufA, dinv, bufB, n);
    k_edge_agg<<<gbE32, 256, 0, stream>>>(src, dst, dinv, bufA, bufB, e);

    // head: out = (bufB + b2) @ Wh + bh
    gemm_kernel<64><<<gbG, 256, 0, stream>>>(bufB, Wh, out, b2, bh, 0, n);
}

// Round 2
// 340.110 us; speedup vs baseline: 8.4650x; 8.4650x over previous
//
#include <hip/hip_runtime.h>

// GCN: 2x GCNConv(128->128) + linear head (128->64), N=50000, E=800000, f32.
// R1: replaced atomicAdd edge-scatter (1.6GB HBM RMW traffic per layer) with
// on-device CSR build + per-node wave gather (no feature atomics).

constexpr int DIM = 128;

// ------------------------------------------------------------ histogram -----
__global__ __launch_bounds__(256) void k_zero_int(int* p, int n) {
    int i = blockIdx.x * 256 + threadIdx.x;
    if (i < n) p[i] = 0;
}

__global__ __launch_bounds__(256) void k_hist(const int* __restrict__ dst,
                                              int* __restrict__ cnt, int e) {
    int i = blockIdx.x * 256 + threadIdx.x;
    if (i < e) atomicAdd(&cnt[dst[i]], 1);
}

// dinv = rsqrt(cnt + 1)  (+1 = self loop)
__global__ __launch_bounds__(256) void k_dinv(const int* __restrict__ cnt,
                                              float* __restrict__ dinv, int n) {
    int i = blockIdx.x * 256 + threadIdx.x;
    if (i < n) dinv[i] = rsqrtf((float)(cnt[i] + 1));
}

// ------------------------------------------------------- exclusive scan -----
// scan1: each block scans 1024 ints (4/thread), writes per-element exclusive
// prefix (intra-block) to off[] and the block total to bsum[].
__global__ __launch_bounds__(256) void k_scan1(const int* __restrict__ cnt,
                                               int* __restrict__ off,
                                               int* __restrict__ bsum, int n) {
    __shared__ int part[256];
    int tid = threadIdx.x;
    int base = blockIdx.x * 1024 + tid * 4;
    int v[4];
    int s = 0;
#pragma unroll
    for (int k = 0; k < 4; ++k) {
        v[k] = s;
        int idx = base + k;
        s += (idx < n) ? cnt[idx] : 0;
    }
    part[tid] = s;
    __syncthreads();
    for (int o = 1; o < 256; o <<= 1) {
        int y = (tid >= o) ? part[tid - o] : 0;
        __syncthreads();
        part[tid] += y;
        __syncthreads();
    }
    int excl = part[tid] - s;   // exclusive across threads in block
#pragma unroll
    for (int k = 0; k < 4; ++k) {
        int idx = base + k;
        if (idx < n) off[idx] = excl + v[k];
    }
    if (tid == 255) bsum[blockIdx.x] = part[255];
}

// scan2: single block scans bsum (nb <= 256) in place -> exclusive.
__global__ __launch_bounds__(256) void k_scan2(int* bsum, int nb) {
    __shared__ int part[256];
    int tid = threadIdx.x;
    int v = (tid < nb) ? bsum[tid] : 0;
    part[tid] = v;
    __syncthreads();
    for (int o = 1; o < 256; o <<= 1) {
        int y = (tid >= o) ? part[tid - o] : 0;
        __syncthreads();
        part[tid] += y;
        __syncthreads();
    }
    if (tid < nb) bsum[tid] = part[tid] - v;
}

// scan3: add block offsets, mirror into cursor, set off[n] = e.
__global__ __launch_bounds__(256) void k_scan3(int* __restrict__ off,
                                               const int* __restrict__ bsum,
                                               int* __restrict__ cursor,
                                               int n, int e) {
    int i = blockIdx.x * 256 + threadIdx.x;
    if (i < n) {
        int o = off[i] + bsum[i >> 10];
        off[i] = o;
        cursor[i] = o;
    }
    if (i == 0) off[n] = e;
}

// ------------------------------------------------------------- scatter ------
__global__ __launch_bounds__(256) void k_scatter(
    const int* __restrict__ src, const int* __restrict__ dst,
    const float* __restrict__ dinv, int* __restrict__ cursor,
    int* __restrict__ csr_src, float* __restrict__ csr_w, int e) {
    int i = blockIdx.x * 256 + threadIdx.x;
    if (i < e) {
        int s = src[i], d = dst[i];
        int pos = atomicAdd(&cursor[d], 1);
        csr_src[pos] = s;
        csr_w[pos] = dinv[s] * dinv[d];
    }
}

// ------------------------------------------------------- per-node gather ----
// One wave (64 lanes) per node; lane holds 2 cols (float2). acc initialized
// with the self-loop term (fuses the old k_selfloop).
__global__ __launch_bounds__(256) void k_gather(
    const int* __restrict__ off, const int* __restrict__ csr_src,
    const float* __restrict__ csr_w, const float* __restrict__ dinv,
    const float* __restrict__ h, float* __restrict__ agg, int n) {
    int wid = threadIdx.x >> 6;
    int lane = threadIdx.x & 63;
    int node = blockIdx.x * 4 + wid;
    if (node >= n) return;
    const float2* h2 = (const float2*)h;
    float d = dinv[node];
    float sl = d * d;
    float2 acc0 = h2[(size_t)node * 64 + lane];
    acc0.x *= sl; acc0.y *= sl;
    float2 acc1 = make_float2(0.f, 0.f);
    int j = off[node];
    int end = off[node + 1];
    for (; j + 2 <= end; j += 2) {
        int s0 = csr_src[j], s1 = csr_src[j + 1];
        float w0 = csr_w[j], w1 = csr_w[j + 1];
        float2 v0 = h2[(size_t)s0 * 64 + lane];
        float2 v1 = h2[(size_t)s1 * 64 + lane];
        acc0.x += v0.x * w0; acc0.y += v0.y * w0;
        acc1.x += v1.x * w1; acc1.y += v1.y * w1;
    }
    if (j < end) {
        int s0 = csr_src[j];
        float w0 = csr_w[j];
        float2 v0 = h2[(size_t)s0 * 64 + lane];
        acc0.x += v0.x * w0; acc0.y += v0.y * w0;
    }
    acc0.x += acc1.x; acc0.y += acc1.y;
    ((float2*)agg)[(size_t)node * 64 + lane] = acc0;
}

// ----------------------------------------------------------------- GEMM -----
// C[n,NCOL] = epilogue_in(A[n,128]) @ B[128,NCOL] (+ bias_out)
template <int NCOL>
__global__ __launch_bounds__(256) void gemm_kernel(
    const float* __restrict__ A, const float* __restrict__ B,
    float* __restrict__ C,
    const float* __restrict__ bias_in, const float* __restrict__ bias_out,
    int relu_in, int n) {
    constexpr int K = DIM;
    constexpr int ROWS = 32;
    constexpr int CH = NCOL / 2;
    constexpr int G = 256 / CH;
    constexpr int RPT = ROWS / G;

    __shared__ float Bs[K * NCOL];
    __shared__ float As[ROWS * K];

    int tid = threadIdx.x;
    int row0 = blockIdx.x * ROWS;

    for (int i = tid * 4; i < K * NCOL; i += 1024)
        *(float4*)&Bs[i] = *(const float4*)&B[i];

    for (int i = tid * 4; i < ROWS * K; i += 1024) {
        int r = i >> 7;
        int k = i & (K - 1);
        int row = row0 + r;
        float4 v = make_float4(0.f, 0.f, 0.f, 0.f);
        if (row < n) {
            v = *(const float4*)&A[(size_t)row * K + k];
            if (bias_in) {
                v.x += bias_in[k + 0];
                v.y += bias_in[k + 1];
                v.z += bias_in[k + 2];
                v.w += bias_in[k + 3];
            }
            if (relu_in) {
                v.x = fmaxf(v.x, 0.f);
                v.y = fmaxf(v.y, 0.f);
                v.z = fmaxf(v.z, 0.f);
                v.w = fmaxf(v.w, 0.f);
            }
        }
        *(float4*)&As[i] = v;
    }
    __syncthreads();

    int c2 = (tid % CH) * 2;
    int rg = tid / CH;

    float acc[RPT][2];
#pragma unroll
    for (int r = 0; r < RPT; ++r) { acc[r][0] = 0.f; acc[r][1] = 0.f; }

    for (int k = 0; k < K; k += 4) {
        float2 b0 = *(const float2*)&Bs[(k + 0) * NCOL + c2];
        float2 b1 = *(const float2*)&Bs[(k + 1) * NCOL + c2];
        float2 b2 = *(const float2*)&Bs[(k + 2) * NCOL + c2];
        float2 b3 = *(const float2*)&Bs[(k + 3) * NCOL + c2];
#pragma unroll
        for (int r = 0; r < RPT; ++r) {
            float4 a4 = *(const float4*)&As[(rg * RPT + r) * K + k];
            acc[r][0] += a4.x * b0.x + a4.y * b1.x + a4.z * b2.x + a4.w * b3.x;
            acc[r][1] += a4.x * b0.y + a4.y * b1.y + a4.z * b2.y + a4.w * b3.y;
        }
    }

#pragma unroll
    for (int r = 0; r < RPT; ++r) {
        int row = row0 + rg * RPT + r;
        if (row < n) {
            float o0 = acc[r][0];
            float o1 = acc[r][1];
            if (bias_out) {
                o0 += bias_out[c2 + 0];
                o1 += bias_out[c2 + 1];
            }
            *(float2*)&C[(size_t)row * NCOL + c2] = make_float2(o0, o1);
        }
    }
}

// --------------------------------------------------------------- launch -----
extern "C" void kernel_launch(void* const* d_in, const int* in_sizes, int n_in,
                              void* d_out, int out_size, void* d_ws, size_t ws_size,
                              hipStream_t stream) {
    const float* x  = (const float*)d_in[0];
    const int*   ei = (const int*)d_in[1];
    const float* W1 = (const float*)d_in[2];
    const float* b1 = (const float*)d_in[3];
    const float* W2 = (const float*)d_in[4];
    const float* b2 = (const float*)d_in[5];
    const float* Wh = (const float*)d_in[6];
    const float* bh = (const float*)d_in[7];
    float* out = (float*)d_out;

    const int n = in_sizes[0] / DIM;       // 50000
    const int e = in_sizes[1] / 2;         // 800000
    const int* src = ei;
    const int* dst = ei + e;

    size_t nAlign = ((size_t)n + 1024) & ~(size_t)255;  // room for off[n]
    float* dinv    = (float*)d_ws;
    int*   cnt     = (int*)(dinv + nAlign);
    int*   off     = (int*)(cnt + nAlign);
    int*   cursor  = (int*)(off + nAlign);
    int*   bsum    = (int*)(cursor + nAlign);
    int*   csr_src = bsum + 256;
    float* csr_w   = (float*)(csr_src + ((size_t)e + 256));
    float* bufA    = csr_w + ((size_t)e + 256);     // [n,128] gemm out
    float* bufB    = bufA + (size_t)n * DIM;        // [n,128] agg out

    int gbN  = (n + 255) / 256;
    int gbE  = (e + 255) / 256;
    int gbS1 = (n + 1023) / 1024;   // 49
    int gbG  = (n + 31) / 32;
    int gbW  = (n + 3) / 4;

    // CSR build + dinv
    k_zero_int<<<gbN, 256, 0, stream>>>(cnt, n);
    k_hist<<<gbE, 256, 0, stream>>>(dst, cnt, e);
    k_dinv<<<gbN, 256, 0, stream>>>(cnt, dinv, n);
    k_scan1<<<gbS1, 256, 0, stream>>>(cnt, off, bsum, n);
    k_scan2<<<1, 256, 0, stream>>>(bsum, gbS1);
    k_scan3<<<gbN, 256, 0, stream>>>(off, bsum, cursor, n, e);
    k_scatter<<<gbE, 256, 0, stream>>>(src, dst, dinv, cursor, csr_src, csr_w, e);

    // layer 1
    gemm_kernel<DIM><<<gbG, 256, 0, stream>>>(x, W1, bufA, nullptr, nullptr, 0, n);
    k_gather<<<gbW, 256, 0, stream>>>(off, csr_src, csr_w, dinv, bufA, bufB, n);

    // layer 2
    gemm_kernel<DIM><<<gbG, 256, 0, stream>>>(bufB, W2, bufA, b1, nullptr, 1, n);
    k_gather<<<gbW, 256, 0, stream>>>(off, csr_src, csr_w, dinv, bufA, bufB, n);

    // head
    gemm_kernel<64><<<gbG, 256, 0, stream>>>(bufB, Wh, out, b2, bh, 0, n);
}

// Round 3
// 257.426 us; speedup vs baseline: 11.1839x; 1.3212x over previous
//
#include <hip/hip_runtime.h>

// GCN: 2x GCNConv(128->128) + head (128->64), N=50000, E=800000, f32.
// R2: fold Wh into W2 (agg is linear) -> gather2 is 64-wide, head GEMM gone.
//     Gather: 32 lanes/node, float4, 4-edge-deep pipeline, packed CSR (src,w).

constexpr int DIM = 128;

// ------------------------------------------------------------ histogram -----
__global__ __launch_bounds__(256) void k_hist(const int* __restrict__ dst,
                                              int* __restrict__ cnt, int e) {
    int i = blockIdx.x * 256 + threadIdx.x;
    if (i < e) atomicAdd(&cnt[dst[i]], 1);
}

// ------------------------------------------------------- exclusive scan -----
// scan1: block scans 1024 ints (4/thread); also computes dinv = rsqrt(cnt+1).
__global__ __launch_bounds__(256) void k_scan1(const int* __restrict__ cnt,
                                               int* __restrict__ off,
                                               int* __restrict__ bsum,
                                               float* __restrict__ dinv, int n) {
    __shared__ int part[256];
    int tid = threadIdx.x;
    int base = blockIdx.x * 1024 + tid * 4;
    int v[4];
    int s = 0;
#pragma unroll
    for (int k = 0; k < 4; ++k) {
        v[k] = s;
        int idx = base + k;
        if (idx < n) {
            int c = cnt[idx];
            s += c;
            dinv[idx] = rsqrtf((float)(c + 1));
        }
    }
    part[tid] = s;
    __syncthreads();
    for (int o = 1; o < 256; o <<= 1) {
        int y = (tid >= o) ? part[tid - o] : 0;
        __syncthreads();
        part[tid] += y;
        __syncthreads();
    }
    int excl = part[tid] - s;
#pragma unroll
    for (int k = 0; k < 4; ++k) {
        int idx = base + k;
        if (idx < n) off[idx] = excl + v[k];
    }
    if (tid == 255) bsum[blockIdx.x] = part[255];
}

__global__ __launch_bounds__(256) void k_scan2(int* bsum, int nb) {
    __shared__ int part[256];
    int tid = threadIdx.x;
    int v = (tid < nb) ? bsum[tid] : 0;
    part[tid] = v;
    __syncthreads();
    for (int o = 1; o < 256; o <<= 1) {
        int y = (tid >= o) ? part[tid - o] : 0;
        __syncthreads();
        part[tid] += y;
        __syncthreads();
    }
    if (tid < nb) bsum[tid] = part[tid] - v;
}

__global__ __launch_bounds__(256) void k_scan3(int* __restrict__ off,
                                               const int* __restrict__ bsum,
                                               int* __restrict__ cursor,
                                               int n, int e) {
    int i = blockIdx.x * 256 + threadIdx.x;
    if (i < n) {
        int o = off[i] + bsum[i >> 10];
        off[i] = o;
        cursor[i] = o;
    }
    if (i == 0) off[n] = e;
}

// ------------------------------------------------------------- scatter ------
// packed CSR entry: .x = src (bit-cast int), .y = edge weight
__global__ __launch_bounds__(256) void k_scatter(
    const int* __restrict__ src, const int* __restrict__ dst,
    const float* __restrict__ dinv, int* __restrict__ cursor,
    float2* __restrict__ csr, int e) {
    int i = blockIdx.x * 256 + threadIdx.x;
    if (i < e) {
        int s = src[i], d = dst[i];
        int pos = atomicAdd(&cursor[d], 1);
        csr[pos] = make_float2(__int_as_float(s), dinv[s] * dinv[d]);
    }
}

// -------------------------------------------------- fold head into layer2 ---
// blocks 0..31: W2h[r,c] = sum_k W2[r,k]*Wh[k,c]   (128x64)
// block 32    : bconst[c] = sum_k b2[k]*Wh[k,c] + bh[c]
__global__ __launch_bounds__(256) void k_foldhead(
    const float* __restrict__ W2, const float* __restrict__ Wh,
    const float* __restrict__ b2, const float* __restrict__ bh,
    float* __restrict__ W2h, float* __restrict__ bconst) {
    if (blockIdx.x == 32) {
        int c = threadIdx.x;
        if (c < 64) {
            float s = bh[c];
            for (int k = 0; k < 128; ++k) s += b2[k] * Wh[k * 64 + c];
            bconst[c] = s;
        }
        return;
    }
    int gid = blockIdx.x * 256 + threadIdx.x;
    int r = gid >> 6, c = gid & 63;
    float s = 0.f;
    for (int k = 0; k < 128; ++k) s += W2[r * 128 + k] * Wh[k * 64 + c];
    W2h[gid] = s;
}

// ------------------------------------------------------- per-node gather ----
__device__ __forceinline__ void fma4(float4& a, const float4& v, float w) {
    a.x += v.x * w; a.y += v.y * w; a.z += v.z * w; a.w += v.w * w;
}
__device__ __forceinline__ void fma2(float2& a, const float2& v, float w) {
    a.x += v.x * w; a.y += v.y * w;
}

// 32 lanes per node, float4 per lane (128 feats). 4 edges in flight.
__global__ __launch_bounds__(256) void k_gather128(
    const int* __restrict__ off, const float2* __restrict__ csr,
    const float* __restrict__ dinv, const float* __restrict__ h,
    float* __restrict__ agg, int n) {
    int g = (blockIdx.x * 256 + threadIdx.x) >> 5;
    int lane = threadIdx.x & 31;
    if (g >= n) return;
    const float4* h4 = (const float4*)h;
    float d = dinv[g];
    float sl = d * d;
    float4 a0 = h4[(size_t)g * 32 + lane];
    a0.x *= sl; a0.y *= sl; a0.z *= sl; a0.w *= sl;
    float4 a1 = make_float4(0.f, 0.f, 0.f, 0.f);
    int j = off[g], end = off[g + 1];
    for (; j + 4 <= end; j += 4) {
        float2 e0 = csr[j + 0], e1 = csr[j + 1];
        float2 e2 = csr[j + 2], e3 = csr[j + 3];
        float4 v0 = h4[(size_t)__float_as_int(e0.x) * 32 + lane];
        float4 v1 = h4[(size_t)__float_as_int(e1.x) * 32 + lane];
        float4 v2 = h4[(size_t)__float_as_int(e2.x) * 32 + lane];
        float4 v3 = h4[(size_t)__float_as_int(e3.x) * 32 + lane];
        fma4(a0, v0, e0.y);
        fma4(a1, v1, e1.y);
        fma4(a0, v2, e2.y);
        fma4(a1, v3, e3.y);
    }
    for (; j < end; ++j) {
        float2 e0 = csr[j];
        float4 v0 = h4[(size_t)__float_as_int(e0.x) * 32 + lane];
        fma4(a0, v0, e0.y);
    }
    a0.x += a1.x; a0.y += a1.y; a0.z += a1.z; a0.w += a1.w;
    ((float4*)agg)[(size_t)g * 32 + lane] = a0;
}

// 32 lanes per node, float2 per lane (64 feats), + bconst epilogue.
__global__ __launch_bounds__(256) void k_gather64(
    const int* __restrict__ off, const float2* __restrict__ csr,
    const float* __restrict__ dinv, const float* __restrict__ h,
    const float* __restrict__ bconst, float* __restrict__ outp, int n) {
    int g = (blockIdx.x * 256 + threadIdx.x) >> 5;
    int lane = threadIdx.x & 31;
    if (g >= n) return;
    const float2* h2 = (const float2*)h;
    float d = dinv[g];
    float sl = d * d;
    float2 a0 = h2[(size_t)g * 32 + lane];
    a0.x *= sl; a0.y *= sl;
    float2 a1 = make_float2(0.f, 0.f);
    int j = off[g], end = off[g + 1];
    for (; j + 4 <= end; j += 4) {
        float2 e0 = csr[j + 0], e1 = csr[j + 1];
        float2 e2 = csr[j + 2], e3 = csr[j + 3];
        float2 v0 = h2[(size_t)__float_as_int(e0.x) * 32 + lane];
        float2 v1 = h2[(size_t)__float_as_int(e1.x) * 32 + lane];
        float2 v2 = h2[(size_t)__float_as_int(e2.x) * 32 + lane];
        float2 v3 = h2[(size_t)__float_as_int(e3.x) * 32 + lane];
        fma2(a0, v0, e0.y);
        fma2(a1, v1, e1.y);
        fma2(a0, v2, e2.y);
        fma2(a1, v3, e3.y);
    }
    for (; j < end; ++j) {
        float2 e0 = csr[j];
        float2 v0 = h2[(size_t)__float_as_int(e0.x) * 32 + lane];
        fma2(a0, v0, e0.y);
    }
    float2 bc = ((const float2*)bconst)[lane];
    a0.x += a1.x + bc.x;
    a0.y += a1.y + bc.y;
    ((float2*)outp)[(size_t)g * 32 + lane] = a0;
}

// ----------------------------------------------------------------- GEMM -----
template <int NCOL>
__global__ __launch_bounds__(256) void gemm_kernel(
    const float* __restrict__ A, const float* __restrict__ B,
    float* __restrict__ C,
    const float* __restrict__ bias_in, const float* __restrict__ bias_out,
    int relu_in, int n) {
    constexpr int K = DIM;
    constexpr int ROWS = 32;
    constexpr int CH = NCOL / 2;
    constexpr int G = 256 / CH;
    constexpr int RPT = ROWS / G;

    __shared__ float Bs[K * NCOL];
    __shared__ float As[ROWS * K];

    int tid = threadIdx.x;
    int row0 = blockIdx.x * ROWS;

    for (int i = tid * 4; i < K * NCOL; i += 1024)
        *(float4*)&Bs[i] = *(const float4*)&B[i];

    for (int i = tid * 4; i < ROWS * K; i += 1024) {
        int r = i >> 7;
        int k = i & (K - 1);
        int row = row0 + r;
        float4 v = make_float4(0.f, 0.f, 0.f, 0.f);
        if (row < n) {
            v = *(const float4*)&A[(size_t)row * K + k];
            if (bias_in) {
                v.x += bias_in[k + 0];
                v.y += bias_in[k + 1];
                v.z += bias_in[k + 2];
                v.w += bias_in[k + 3];
            }
            if (relu_in) {
                v.x = fmaxf(v.x, 0.f);
                v.y = fmaxf(v.y, 0.f);
                v.z = fmaxf(v.z, 0.f);
                v.w = fmaxf(v.w, 0.f);
            }
        }
        *(float4*)&As[i] = v;
    }
    __syncthreads();

    int c2 = (tid % CH) * 2;
    int rg = tid / CH;

    float acc[RPT][2];
#pragma unroll
    for (int r = 0; r < RPT; ++r) { acc[r][0] = 0.f; acc[r][1] = 0.f; }

    for (int k = 0; k < K; k += 4) {
        float2 b0 = *(const float2*)&Bs[(k + 0) * NCOL + c2];
        float2 b1 = *(const float2*)&Bs[(k + 1) * NCOL + c2];
        float2 b2 = *(const float2*)&Bs[(k + 2) * NCOL + c2];
        float2 b3 = *(const float2*)&Bs[(k + 3) * NCOL + c2];
#pragma unroll
        for (int r = 0; r < RPT; ++r) {
            float4 a4 = *(const float4*)&As[(rg * RPT + r) * K + k];
            acc[r][0] += a4.x * b0.x + a4.y * b1.x + a4.z * b2.x + a4.w * b3.x;
            acc[r][1] += a4.x * b0.y + a4.y * b1.y + a4.z * b2.y + a4.w * b3.y;
        }
    }

#pragma unroll
    for (int r = 0; r < RPT; ++r) {
        int row = row0 + rg * RPT + r;
        if (row < n) {
            float o0 = acc[r][0];
            float o1 = acc[r][1];
            if (bias_out) {
                o0 += bias_out[c2 + 0];
                o1 += bias_out[c2 + 1];
            }
            *(float2*)&C[(size_t)row * NCOL + c2] = make_float2(o0, o1);
        }
    }
}

// --------------------------------------------------------------- launch -----
extern "C" void kernel_launch(void* const* d_in, const int* in_sizes, int n_in,
                              void* d_out, int out_size, void* d_ws, size_t ws_size,
                              hipStream_t stream) {
    const float* x  = (const float*)d_in[0];
    const int*   ei = (const int*)d_in[1];
    const float* W1 = (const float*)d_in[2];
    const float* b1 = (const float*)d_in[3];
    const float* W2 = (const float*)d_in[4];
    const float* b2 = (const float*)d_in[5];
    const float* Wh = (const float*)d_in[6];
    const float* bh = (const float*)d_in[7];
    float* out = (float*)d_out;

    const int n = in_sizes[0] / DIM;       // 50000
    const int e = in_sizes[1] / 2;         // 800000
    const int* src = ei;
    const int* dst = ei + e;

    size_t nAlign = ((size_t)n + 1024) & ~(size_t)255;
    float*  dinv    = (float*)d_ws;
    int*    cnt     = (int*)(dinv + nAlign);
    int*    off     = (int*)(cnt + nAlign);
    int*    cursor  = (int*)(off + nAlign);
    int*    bsum    = (int*)(cursor + nAlign);
    float*  W2h     = (float*)(bsum + 256);          // 128*64
    float*  bconst  = W2h + 128 * 64;                // 64
    float2* csr     = (float2*)(bconst + 64 + 64);   // e entries, 8B each
    float*  bufA    = (float*)(csr + ((size_t)e + 64));  // [n,128]
    float*  bufB    = bufA + (size_t)n * DIM;            // [n,128]

    int gbN  = (n + 255) / 256;
    int gbE  = (e + 255) / 256;
    int gbS1 = (n + 1023) / 1024;
    int gbG  = (n + 31) / 32;
    int gbW  = (n + 7) / 8;

    // CSR build + dinv + head fold
    hipMemsetAsync(cnt, 0, (size_t)n * 4, stream);
    k_hist<<<gbE, 256, 0, stream>>>(dst, cnt, e);
    k_scan1<<<gbS1, 256, 0, stream>>>(cnt, off, bsum, dinv, n);
    k_scan2<<<1, 256, 0, stream>>>(bsum, gbS1);
    k_scan3<<<gbN, 256, 0, stream>>>(off, bsum, cursor, n, e);
    k_scatter<<<gbE, 256, 0, stream>>>(src, dst, dinv, cursor, csr, e);
    k_foldhead<<<33, 256, 0, stream>>>(W2, Wh, b2, bh, W2h, bconst);

    // layer 1: bufA = x@W1 ; bufB = agg(bufA)
    gemm_kernel<DIM><<<gbG, 256, 0, stream>>>(x, W1, bufA, nullptr, nullptr, 0, n);
    k_gather128<<<gbW, 256, 0, stream>>>(off, csr, dinv, bufA, bufB, n);

    // layer 2 + head folded: bufA[:, :64] = relu(bufB + b1) @ W2h
    gemm_kernel<64><<<gbG, 256, 0, stream>>>(bufB, W2h, bufA, b1, nullptr, 1, n);
    // out = agg(bufA) + bconst
    k_gather64<<<gbW, 256, 0, stream>>>(off, csr, dinv, bufA, bconst, out, n);
}

// Round 4
// 170.513 us; speedup vs baseline: 16.8845x; 1.5097x over previous
//
#include <hip/hip_runtime.h>

// GCN: 2x GCNConv(128->128) + head (128->64), N=50000, E=800000.
// R3: fp16 MFMA GEMMs (weights pre-packed to fragment layout), fp16 feature
// storage (halves gather traffic), b1+relu folded into gather-1 epilogue,
// 9 dispatches total.

typedef _Float16 half8 __attribute__((ext_vector_type(8)));
typedef _Float16 half4v __attribute__((ext_vector_type(4)));
typedef _Float16 half2v __attribute__((ext_vector_type(2)));
typedef float f32x4 __attribute__((ext_vector_type(4)));

constexpr int DIM = 128;

// ---------------------------------------------------------------- prep ------
// blocks 0..31 : W2h = W2 @ Wh (f32, 128x64)
// block  32    : bconst = b2 @ Wh + bh (64)
// blocks 33..40: zero cnt[n]
// blocks 41..48: pack W1 -> W1p fp16 fragments (ks 0..3, ct 0..7)
__global__ __launch_bounds__(256) void k_prep(
    const float* __restrict__ W1, const float* __restrict__ W2,
    const float* __restrict__ Wh, const float* __restrict__ b2,
    const float* __restrict__ bh, float* __restrict__ W2h,
    float* __restrict__ bconst, _Float16* __restrict__ W1p,
    int* __restrict__ cnt, int n) {
    int b = blockIdx.x, t = threadIdx.x;
    if (b < 32) {
        int gid = b * 256 + t;
        int r = gid >> 6, c = gid & 63;
        float s = 0.f;
        for (int k = 0; k < 128; ++k) s += W2[r * 128 + k] * Wh[k * 64 + c];
        W2h[gid] = s;
    } else if (b == 32) {
        if (t < 64) {
            float s = bh[t];
            for (int k = 0; k < 128; ++k) s += b2[k] * Wh[k * 64 + t];
            bconst[t] = s;
        }
    } else if (b < 41) {
        for (int i = (b - 33) * 256 + t; i < n; i += 8 * 256) cnt[i] = 0;
    } else {
        int q = (b - 41) * 256 + t;         // 0..2047 fragment chunks
        int lane = q & 63, ct = (q >> 6) & 7, ks = q >> 9;
        int kb = 32 * ks + 8 * (lane >> 4);
        int col = 16 * ct + (lane & 15);
        half8 v;
#pragma unroll
        for (int i = 0; i < 8; ++i) v[i] = (_Float16)W1[(kb + i) * 128 + col];
        *(half8*)&W1p[(size_t)q * 8] = v;
    }
}

// ------------------------------------------------------------ histogram -----
__global__ __launch_bounds__(256) void k_hist(const int* __restrict__ dst,
                                              int* __restrict__ cnt, int e) {
    int i = blockIdx.x * 256 + threadIdx.x;
    if (i < e) atomicAdd(&cnt[dst[i]], 1);
}

// ------------------------------------------------------- scan + W2h pack ----
// blocks 0..nb-1: per-block scan of 1024 counts + dinv; last block: pack W2h.
__global__ __launch_bounds__(256) void k_scan1(
    const int* __restrict__ cnt, int* __restrict__ off,
    int* __restrict__ bsum, float* __restrict__ dinv,
    const float* __restrict__ W2h, _Float16* __restrict__ W2p, int n) {
    if (blockIdx.x == gridDim.x - 1) {
        int q0 = threadIdx.x * 4;
#pragma unroll
        for (int j = 0; j < 4; ++j) {
            int q = q0 + j;                 // 0..1023
            int lane = q & 63, ct = (q >> 6) & 3, ks = q >> 8;
            int kb = 32 * ks + 8 * (lane >> 4);
            int col = 16 * ct + (lane & 15);
            half8 v;
#pragma unroll
            for (int i = 0; i < 8; ++i) v[i] = (_Float16)W2h[(kb + i) * 64 + col];
            *(half8*)&W2p[(size_t)q * 8] = v;
        }
        return;
    }
    __shared__ int part[256];
    int tid = threadIdx.x;
    int base = blockIdx.x * 1024 + tid * 4;
    int v[4];
    int s = 0;
#pragma unroll
    for (int k = 0; k < 4; ++k) {
        v[k] = s;
        int idx = base + k;
        if (idx < n) {
            int c = cnt[idx];
            s += c;
            dinv[idx] = rsqrtf((float)(c + 1));
        }
    }
    part[tid] = s;
    __syncthreads();
    for (int o = 1; o < 256; o <<= 1) {
        int y = (tid >= o) ? part[tid - o] : 0;
        __syncthreads();
        part[tid] += y;
        __syncthreads();
    }
    int excl = part[tid] - s;
#pragma unroll
    for (int k = 0; k < 4; ++k) {
        int idx = base + k;
        if (idx < n) off[idx] = excl + v[k];
    }
    if (tid == 255) bsum[blockIdx.x] = part[255];
}

// scan3: block-local prefix of bsum via wave reduce, finalize off + cursor.
__global__ __launch_bounds__(256) void k_scan3(int* __restrict__ off,
                                               const int* __restrict__ bsum,
                                               int* __restrict__ cursor,
                                               int n, int e, int nb) {
    __shared__ int sbase;
    int t = threadIdx.x;
    int need = blockIdx.x >> 2;   // bsum prefix needed by this block
    if (t < 64) {
        int v = (t < need && t < nb) ? bsum[t] : 0;
#pragma unroll
        for (int o = 32; o; o >>= 1) v += __shfl_down(v, o);
        if (t == 0) sbase = v;
    }
    __syncthreads();
    int i = blockIdx.x * 256 + t;
    if (i < n) {
        int o = off[i] + sbase;
        off[i] = o;
        cursor[i] = o;
    }
    if (i == 0) off[n] = e;
}

// ------------------------------------------------------------- scatter ------
__global__ __launch_bounds__(256) void k_scatter(
    const int* __restrict__ src, const int* __restrict__ dst,
    const float* __restrict__ dinv, int* __restrict__ cursor,
    float2* __restrict__ csr, int e) {
    int i = blockIdx.x * 256 + threadIdx.x;
    if (i < e) {
        int s = src[i], d = dst[i];
        int pos = atomicAdd(&cursor[d], 1);
        csr[pos] = make_float2(__int_as_float(s), dinv[s] * dinv[d]);
    }
}

// ------------------------------------------------------------ MFMA GEMM -----
// C[n,NCOL] (fp16) = A[n,128] @ B[128,NCOL]; B pre-packed fp16 frags.
// Block: 64 rows, 4 waves (16 rows each), 16x16x32 fp16 MFMA, f32 accum.
template <int NCOL, bool AF16>
__global__ __launch_bounds__(256) void k_gemm(
    const void* __restrict__ Asrc, const _Float16* __restrict__ Bp,
    _Float16* __restrict__ Cout, int n) {
    constexpr int CT = NCOL / 16;          // col tiles: 8 or 4
    constexpr int BCHUNK = 4 * CT * 64;    // 16B frag chunks of B
    __shared__ _Float16 Bs[BCHUNK * 8];    // 32KB / 16KB
    __shared__ _Float16 As[8192];          // 16KB frag store, reused as epilogue

    int tid = threadIdx.x;
    int row0 = blockIdx.x * 64;

    {   // stage packed B linearly
        const uint4* sp = (const uint4*)Bp;
        uint4* dp = (uint4*)Bs;
        for (int i = tid; i < BCHUNK; i += 256) dp[i] = sp[i];
    }
    // stage A as packed fragments (convert f32->fp16 if needed)
    for (int c = tid; c < 1024; c += 256) {
        int r = c >> 4, kc = c & 15;
        int row = row0 + r;
        half8 v;
#pragma unroll
        for (int i = 0; i < 8; ++i) v[i] = (_Float16)0.f;
        if (row < n) {
            if constexpr (AF16) {
                v = *(const half8*)((const _Float16*)Asrc + (size_t)row * 128 + kc * 8);
            } else {
                const float* p = (const float*)Asrc + (size_t)row * 128 + kc * 8;
                f32x4 lo = *(const f32x4*)p;
                f32x4 hi = *(const f32x4*)(p + 4);
                v[0] = (_Float16)lo[0]; v[1] = (_Float16)lo[1];
                v[2] = (_Float16)lo[2]; v[3] = (_Float16)lo[3];
                v[4] = (_Float16)hi[0]; v[5] = (_Float16)hi[1];
                v[6] = (_Float16)hi[2]; v[7] = (_Float16)hi[3];
            }
        }
        int dstc = ((r >> 4) * 4 + (kc >> 2)) * 64 + (r & 15) + 16 * (kc & 3);
        *(half8*)&As[dstc * 8] = v;
    }
    __syncthreads();

    int w = tid >> 6, lane = tid & 63;
    f32x4 acc[CT];
#pragma unroll
    for (int ct = 0; ct < CT; ++ct) acc[ct] = (f32x4){0.f, 0.f, 0.f, 0.f};
#pragma unroll
    for (int ks = 0; ks < 4; ++ks) {
        half8 a = *(const half8*)&As[((w * 4 + ks) * 64 + lane) * 8];
#pragma unroll
        for (int ct = 0; ct < CT; ++ct) {
            half8 b = *(const half8*)&Bs[((ks * CT + ct) * 64 + lane) * 8];
            acc[ct] = __builtin_amdgcn_mfma_f32_16x16x32_f16(a, b, acc[ct], 0, 0, 0);
        }
    }
    __syncthreads();   // all frag reads done; reuse As as [64][NCOL] fp16

    int rg = lane >> 4, cl = lane & 15;
#pragma unroll
    for (int ct = 0; ct < CT; ++ct)
#pragma unroll
        for (int r = 0; r < 4; ++r)
            As[(16 * w + 4 * rg + r) * NCOL + 16 * ct + cl] = (_Float16)acc[ct][r];
    __syncthreads();

    constexpr int CHROW = NCOL / 8;
    for (int c = tid; c < 64 * CHROW; c += 256) {
        int r = c / CHROW;
        int row = row0 + r;
        if (row < n)
            *(half8*)(Cout + (size_t)row * NCOL + (size_t)(c - r * CHROW) * 8) =
                *(const half8*)&As[c * 8];
    }
}

// ------------------------------------------------------- gather layer 1 -----
// 32 lanes/node, 4 fp16 feats per lane, 4-edge pipeline.
// Epilogue: + b1, relu, cast fp16 (feeds GEMM2 directly).
__global__ __launch_bounds__(256) void k_gather_l1(
    const int* __restrict__ off, const float2* __restrict__ csr,
    const float* __restrict__ dinv, const _Float16* __restrict__ h,
    const float* __restrict__ bias, _Float16* __restrict__ hA, int n) {
    int g = (blockIdx.x * 256 + threadIdx.x) >> 5;
    int lane = threadIdx.x & 31;
    if (g >= n) return;
    const half4v* h4 = (const half4v*)h;
    float d = dinv[g];
    float sl = d * d;
    half4v hv = h4[(size_t)g * 32 + lane];
    float a0 = (float)hv[0] * sl, a1 = (float)hv[1] * sl;
    float a2 = (float)hv[2] * sl, a3 = (float)hv[3] * sl;
    float c0 = 0.f, c1 = 0.f, c2 = 0.f, c3 = 0.f;
    int j = off[g], end = off[g + 1];
    for (; j + 4 <= end; j += 4) {
        float2 e0 = csr[j + 0], e1 = csr[j + 1];
        float2 e2 = csr[j + 2], e3 = csr[j + 3];
        half4v v0 = h4[(size_t)__float_as_int(e0.x) * 32 + lane];
        half4v v1 = h4[(size_t)__float_as_int(e1.x) * 32 + lane];
        half4v v2 = h4[(size_t)__float_as_int(e2.x) * 32 + lane];
        half4v v3 = h4[(size_t)__float_as_int(e3.x) * 32 + lane];
        a0 += (float)v0[0] * e0.y; a1 += (float)v0[1] * e0.y;
        a2 += (float)v0[2] * e0.y; a3 += (float)v0[3] * e0.y;
        c0 += (float)v1[0] * e1.y; c1 += (float)v1[1] * e1.y;
        c2 += (float)v1[2] * e1.y; c3 += (float)v1[3] * e1.y;
        a0 += (float)v2[0] * e2.y; a1 += (float)v2[1] * e2.y;
        a2 += (float)v2[2] * e2.y; a3 += (float)v2[3] * e2.y;
        c0 += (float)v3[0] * e3.y; c1 += (float)v3[1] * e3.y;
        c2 += (float)v3[2] * e3.y; c3 += (float)v3[3] * e3.y;
    }
    for (; j < end; ++j) {
        float2 e0 = csr[j];
        half4v v0 = h4[(size_t)__float_as_int(e0.x) * 32 + lane];
        a0 += (float)v0[0] * e0.y; a1 += (float)v0[1] * e0.y;
        a2 += (float)v0[2] * e0.y; a3 += (float)v0[3] * e0.y;
    }
    f32x4 bb = *(const f32x4*)(bias + lane * 4);
    half4v o;
    o[0] = (_Float16)fmaxf(a0 + c0 + bb[0], 0.f);
    o[1] = (_Float16)fmaxf(a1 + c1 + bb[1], 0.f);
    o[2] = (_Float16)fmaxf(a2 + c2 + bb[2], 0.f);
    o[3] = (_Float16)fmaxf(a3 + c3 + bb[3], 0.f);
    *(half4v*)(hA + (size_t)g * 128 + lane * 4) = o;
}

// ------------------------------------------------------- gather layer 2 -----
// 32 lanes/node, 2 fp16 feats per lane; epilogue adds bconst, writes f32 out.
__global__ __launch_bounds__(256) void k_gather_l2(
    const int* __restrict__ off, const float2* __restrict__ csr,
    const float* __restrict__ dinv, const _Float16* __restrict__ h2,
    const float* __restrict__ bconst, float* __restrict__ outp, int n) {
    int g = (blockIdx.x * 256 + threadIdx.x) >> 5;
    int lane = threadIdx.x & 31;
    if (g >= n) return;
    const half2v* hp = (const half2v*)h2;
    float d = dinv[g];
    float sl = d * d;
    half2v hv = hp[(size_t)g * 32 + lane];
    float a0 = (float)hv[0] * sl, a1 = (float)hv[1] * sl;
    float c0 = 0.f, c1 = 0.f;
    int j = off[g], end = off[g + 1];
    for (; j + 4 <= end; j += 4) {
        float2 e0 = csr[j + 0], e1 = csr[j + 1];
        float2 e2 = csr[j + 2], e3 = csr[j + 3];
        half2v v0 = hp[(size_t)__float_as_int(e0.x) * 32 + lane];
        half2v v1 = hp[(size_t)__float_as_int(e1.x) * 32 + lane];
        half2v v2 = hp[(size_t)__float_as_int(e2.x) * 32 + lane];
        half2v v3 = hp[(size_t)__float_as_int(e3.x) * 32 + lane];
        a0 += (float)v0[0] * e0.y; a1 += (float)v0[1] * e0.y;
        c0 += (float)v1[0] * e1.y; c1 += (float)v1[1] * e1.y;
        a0 += (float)v2[0] * e2.y; a1 += (float)v2[1] * e2.y;
        c0 += (float)v3[0] * e3.y; c1 += (float)v3[1] * e3.y;
    }
    for (; j < end; ++j) {
        float2 e0 = csr[j];
        half2v v0 = hp[(size_t)__float_as_int(e0.x) * 32 + lane];
        a0 += (float)v0[0] * e0.y; a1 += (float)v0[1] * e0.y;
    }
    float2 bc = *(const float2*)(bconst + lane * 2);
    *(float2*)(outp + (size_t)g * 64 + lane * 2) =
        make_float2(a0 + c0 + bc.x, a1 + c1 + bc.y);
}

// --------------------------------------------------------------- launch -----
extern "C" void kernel_launch(void* const* d_in, const int* in_sizes, int n_in,
                              void* d_out, int out_size, void* d_ws, size_t ws_size,
                              hipStream_t stream) {
    const float* x  = (const float*)d_in[0];
    const int*   ei = (const int*)d_in[1];
    const float* W1 = (const float*)d_in[2];
    const float* b1 = (const float*)d_in[3];
    const float* W2 = (const float*)d_in[4];
    const float* b2 = (const float*)d_in[5];
    const float* Wh = (const float*)d_in[6];
    const float* bh = (const float*)d_in[7];
    float* out = (float*)d_out;

    const int n = in_sizes[0] / DIM;       // 50000
    const int e = in_sizes[1] / 2;         // 800000
    const int* src = ei;
    const int* dst = ei + e;

    char* wsp = (char*)d_ws;
    auto alloc = [&](size_t bytes) {
        char* p = wsp;
        wsp += (bytes + 255) & ~(size_t)255;
        return p;
    };
    float*     dinv   = (float*)alloc((size_t)n * 4);
    int*       cnt    = (int*)alloc((size_t)n * 4);
    int*       off    = (int*)alloc((size_t)(n + 1) * 4);
    int*       cursor = (int*)alloc((size_t)n * 4);
    int*       bsum   = (int*)alloc(256 * 4);
    float*     W2h    = (float*)alloc(8192 * 4);
    float*     bconst = (float*)alloc(64 * 4);
    _Float16*  W1p    = (_Float16*)alloc(16384 * 2);
    _Float16*  W2p    = (_Float16*)alloc(8192 * 2);
    float2*    csr    = (float2*)alloc((size_t)e * 8);
    _Float16*  hbuf   = (_Float16*)alloc((size_t)n * 128 * 2);
    _Float16*  hA     = (_Float16*)alloc((size_t)n * 128 * 2);
    _Float16*  h2     = (_Float16*)alloc((size_t)n * 64 * 2);

    int gbN = (n + 255) / 256;
    int gbE = (e + 255) / 256;
    int gbS1 = (n + 1023) / 1024;          // 49
    int gbGemm = (n + 63) / 64;            // 782
    int gbW = (n + 7) / 8;                 // 6250

    k_prep<<<49, 256, 0, stream>>>(W1, W2, Wh, b2, bh, W2h, bconst, W1p, cnt, n);
    k_hist<<<gbE, 256, 0, stream>>>(dst, cnt, e);
    k_scan1<<<gbS1 + 1, 256, 0, stream>>>(cnt, off, bsum, dinv, W2h, W2p, n);
    k_scan3<<<gbN, 256, 0, stream>>>(off, bsum, cursor, n, e, gbS1);
    k_scatter<<<gbE, 256, 0, stream>>>(src, dst, dinv, cursor, csr, e);

    k_gemm<128, false><<<gbGemm, 256, 0, stream>>>((const void*)x, W1p, hbuf, n);
    k_gather_l1<<<gbW, 256, 0, stream>>>(off, csr, dinv, hbuf, b1, hA, n);
    k_gemm<64, true><<<gbGemm, 256, 0, stream>>>((const void*)hA, W2p, h2, n);
    k_gather_l2<<<gbW, 256, 0, stream>>>(off, csr, dinv, h2, bconst, out, n);
}